// Round 5
// baseline (156.015 us; speedup 1.0000x reference)
//
#include <hip/hip_runtime.h>

#define LROW 136   // padded LDS row stride in bf16 elements (128 + 8); 272 B rows

typedef __bf16 bf16x8  __attribute__((ext_vector_type(8)));
typedef __bf16 bf16x4v __attribute__((ext_vector_type(4)));
typedef __bf16 bf16x2v __attribute__((ext_vector_type(2)));
typedef float  f32x4   __attribute__((ext_vector_type(4)));
typedef float  f32x2   __attribute__((ext_vector_type(2)));

#define MFMA16(a, b, c) __builtin_amdgcn_mfma_f32_16x16x32_bf16((a), (b), (c), 0, 0, 0)

__device__ __forceinline__ float bflo(unsigned v) { return __uint_as_float(v << 16); }
__device__ __forceinline__ float bfhi(unsigned v) { return __uint_as_float(v & 0xffff0000u); }

__device__ __forceinline__ unsigned short f2bf_u16(float f) {
  unsigned u = __float_as_uint(f);
  u += 0x7fffu + ((u >> 16) & 1u);
  return (unsigned short)(u >> 16);
}

// ---------------------------------------------------------------------------
// Kernel 1: fold linear layers into combined weight matrices (bf16, [n][k]
// transposed layout) + folded bias vectors (f32). Bias reductions parallel
// (blocks 321-323).
//   WA = pre_W2 @ msg_W1[0:128]     WB = pre_W2 @ msg_W1[128:256]
//   WD = pre_W2 @ post_W1[128:256]  WC = msg_W2 @ post_W1[0:128]
//   WO = post_W2 @ out_W1           Wo2T = out_W2^T
//   vecs = [w1d | cAB | cP | cO]
// ---------------------------------------------------------------------------
__global__ void combine_weights(
    const float* __restrict__ pre_W2, const float* __restrict__ msg_W1,
    const float* __restrict__ msg_W2, const float* __restrict__ post_W1,
    const float* __restrict__ post_W2, const float* __restrict__ out_W1,
    const float* __restrict__ out_W2, const float* __restrict__ pre_b2,
    const float* __restrict__ msg_b1, const float* __restrict__ msg_b2,
    const float* __restrict__ post_b1, const float* __restrict__ post_b2,
    const float* __restrict__ out_b1,
    unsigned short* __restrict__ WabT, unsigned short* __restrict__ WdT,
    unsigned short* __restrict__ WcT, unsigned short* __restrict__ WoT,
    unsigned short* __restrict__ Wo2T, float* __restrict__ vecs)
{
  __shared__ float part[256];
  const int b = blockIdx.x;
  const int t = threadIdx.x;
  if (b < 320) {
    const int p  = b >> 6;
    const int kp = b & 63;
    const int k  = kp * 2 + (t >> 7);
    const int n  = t & 127;
    const float* L; const float* R; unsigned short* O;
    if (p == 0)      { L = pre_W2;  R = msg_W1;             O = WabT; }
    else if (p == 1) { L = pre_W2;  R = msg_W1 + 128*128;   O = WabT + 128*128; }
    else if (p == 2) { L = pre_W2;  R = post_W1 + 128*128;  O = WdT; }
    else if (p == 3) { L = msg_W2;  R = post_W1;            O = WcT; }
    else             { L = post_W2; R = out_W1;             O = WoT; }
    const float* Lr = L + k * 128;
    float a0 = 0.f, a1 = 0.f, a2 = 0.f, a3 = 0.f;
    #pragma unroll 8
    for (int m = 0; m < 128; m += 4) {
      a0 = fmaf(Lr[m + 0], R[(m + 0) * 128 + n], a0);
      a1 = fmaf(Lr[m + 1], R[(m + 1) * 128 + n], a1);
      a2 = fmaf(Lr[m + 2], R[(m + 2) * 128 + n], a2);
      a3 = fmaf(Lr[m + 3], R[(m + 3) * 128 + n], a3);
    }
    O[n * 128 + k] = f2bf_u16((a0 + a1) + (a2 + a3));
  } else if (b == 320) {
    for (int idx = t; idx < 16 * 128; idx += 256) {
      int o = idx >> 7, k = idx & 127;
      Wo2T[o * 128 + k] = f2bf_u16(out_W2[k * 16 + o]);
    }
    if (t < 128) vecs[t] = msg_W1[256 * 128 + t];          // w1d
  } else {
    const int n = t & 127;
    const int h = t >> 7;
    float s = 0.f;
    if (b == 321) {            // cAB = pre_b2@(W1a+W1b) + msg_b1
      #pragma unroll 8
      for (int m = h * 64; m < h * 64 + 64; ++m)
        s = fmaf(pre_b2[m], msg_W1[m * 128 + n] + msg_W1[(128 + m) * 128 + n], s);
    } else if (b == 322) {     // cP = 7*msg_b2@P1a + pre_b2@P1b + post_b1
      #pragma unroll 8
      for (int m = h * 64; m < h * 64 + 64; ++m) {
        s = fmaf(7.f * msg_b2[m], post_W1[m * 128 + n], s);
        s = fmaf(pre_b2[m], post_W1[(128 + m) * 128 + n], s);
      }
    } else {                   // cO = 8*post_b2@out_W1 + out_b1
      #pragma unroll 8
      for (int m = h * 64; m < h * 64 + 64; ++m)
        s = fmaf(8.f * post_b2[m], out_W1[m * 128 + n], s);
    }
    part[t] = s;
    __syncthreads();
    if (t < 128) {
      float r = part[t] + part[t + 128];
      if (b == 321)      vecs[128 + t] = r + msg_b1[t];
      else if (b == 322) vecs[256 + t] = r + post_b1[t];
      else               vecs[384 + t] = r + out_b1[t];
    }
  }
}

// ---------------------------------------------------------------------------
// Kernel 2: fully fused RRN. One block = 8 graphs = 64 node-rows.
// R4 established: occupancy gated by VGPR+AGPR combined; 4 blocks/CU with
// split phase-2 passes (peak 16 accs). R5: phases 1 & 4 rewritten on packed
// f32x2 (v_pk_fma/add/max_f32) -- the kernel is VALU-issue-bound (42% busy).
// ---------------------------------------------------------------------------
__global__ void __launch_bounds__(256, 4) rrn_main(
    const int* __restrict__ anchors, const int* __restrict__ n_jumps,
    const float* __restrict__ positions, const int* __restrict__ colors,
    const int* __restrict__ markers, const float* __restrict__ pre_W1,
    const float* __restrict__ pre_b1,
    const __bf16* __restrict__ WabT, const __bf16* __restrict__ WdT,
    const __bf16* __restrict__ WcT, const __bf16* __restrict__ WoT,
    const __bf16* __restrict__ Wo2T, const float* __restrict__ vecs,
    const float* __restrict__ out_b2, float* __restrict__ out)
{
  __shared__ __align__(16) char smem[38912];
  // R0 [0,17408): phases 0-1: sW1s[18*128] f32 @0, qrow[8*128] f32 @9216,
  //               posL @13312, cmk @13824. Phase 2+: Ab [64][LROW] (A, then S in place).
  // R1 [17408,34816): h1 [64][LROW] (phases 1-2); Bb (B) after pass D;
  //               Sph @17408 / hob @21760 (phases 5+).
  // dist f32[512] @34816; vec f32[512] @36864.
  __bf16* Ab   = (__bf16*)(smem);
  float*  sW1s = (float*)(smem);
  float*  qrow = (float*)(smem + 9216);
  float*  posL = (float*)(smem + 13312);
  int*    cmk  = (int*)(smem + 13824);
  __bf16* h1   = (__bf16*)(smem + 17408);
  __bf16* Bb   = (__bf16*)(smem + 17408);
  __bf16* Sph  = (__bf16*)(smem + 17408);
  __bf16* hob  = (__bf16*)(smem + 21760);
  float*  dist = (float*)(smem + 34816);
  float*  vec  = (float*)(smem + 36864);

  const int tid  = threadIdx.x;
  const int lane = tid & 63;
  const int w    = tid >> 6;      // wave 0..3
  const int l15  = lane & 15;
  const int quad = lane >> 4;
  const int colw = w * 32;        // this wave's 32-col slice of A/B/D/ph
  const int g0   = blockIdx.x * 8;
  const int n0   = blockIdx.x * 64;

  // ---- phase 0: stage pre_W1 rows 0..17, per-graph qrow, node data, dist, vec
  for (int i = tid; i < 18 * 128; i += 256) sW1s[i] = pre_W1[i];
  {
    const int n = tid & 127;
    for (int g = (tid >> 7); g < 8; g += 2) {
      int a = anchors[g0 + g], nj = n_jumps[g0 + g];
      qrow[g * 128 + n] = pre_b1[n] + pre_W1[(18 + a) * 128 + n]
                        + pre_W1[(34 + nj) * 128 + n];
    }
  }
  if (tid < 128) posL[tid] = positions[n0 * 2 + tid];
  else if (tid < 192) {
    int node = tid - 128;
    cmk[node] = colors[n0 + node] | ((markers[n0 + node] - 8) << 8);
  }
  for (int i = tid; i < 512; i += 256) {
    int g = i >> 6, ii = (i >> 3) & 7, jj = i & 7;
    const float* pa = positions + (n0 + g * 8 + ii) * 2;
    const float* pb = positions + (n0 + g * 8 + jj) * 2;
    float dx = pa[0] - pb[0], dy = pa[1] - pb[1];
    dist[i] = sqrtf(dx * dx + dy * dy);
  }
  for (int i = tid; i < 512; i += 256) vec[i] = vecs[i];
  __syncthreads();

  // ---- phase 1: h1 = relu(feat @ pre_W1 + pre_b1), packed f32x2.
  //      Thread owns dim-pair p, 16 rows; per-thread weight rows hoisted.
  {
    const int p  = (tid & 63) * 2;
    const int rh = tid >> 6;
    const f32x2 z2 = {0.f, 0.f};
    const f32x2 wx = *(const f32x2*)&sW1s[p];          // pos.x weight pair
    const f32x2 wy = *(const f32x2*)&sW1s[128 + p];    // pos.y weight pair
    #pragma unroll 4
    for (int rr = 0; rr < 16; ++rr) {
      int r = rh * 16 + rr;
      float px = posL[r * 2], py = posL[r * 2 + 1];    // broadcast reads
      int cm = cmk[r];
      int c = cm & 255, mk = cm >> 8;
      f32x2 acc = *(const f32x2*)&qrow[(r >> 3) * 128 + p];
      acc += *(const f32x2*)&sW1s[(2 + c) * 128 + p];
      acc += *(const f32x2*)&sW1s[(10 + mk) * 128 + p];
      f32x2 px2 = {px, px}, py2 = {py, py};
      acc = __builtin_elementwise_fma(px2, wx, acc);
      acc = __builtin_elementwise_fma(py2, wy, acc);
      acc = __builtin_elementwise_max(acc, z2);
      bf16x2v o = { (__bf16)acc.x, (__bf16)acc.y };
      *(bf16x2v*)&h1[r * LROW + p] = o;
    }
  }
  __syncthreads();

  // ---- phase 2 pass 1: [A|B] cols colw..colw+31 each = h1 @ WabT (16 accs)
  f32x4 acc1[4][4];   // nt 0,1 -> A cols colw+nt*16; nt 2,3 -> B cols colw+(nt-2)*16
  {
    f32x4 zero = {0.f, 0.f, 0.f, 0.f};
    #pragma unroll
    for (int mt = 0; mt < 4; ++mt)
      #pragma unroll
      for (int nt = 0; nt < 4; ++nt) acc1[mt][nt] = zero;
  }
  #pragma unroll
  for (int kb = 0; kb < 128; kb += 32) {
    const int ko = kb + quad * 8;
    bf16x8 fa[4], fb[4];
    #pragma unroll
    for (int mt = 0; mt < 4; ++mt)
      fa[mt] = *(const bf16x8*)&h1[(mt * 16 + l15) * LROW + ko];
    fb[0] = *(const bf16x8*)&WabT[(colw + l15) * 128 + ko];
    fb[1] = *(const bf16x8*)&WabT[(colw + 16 + l15) * 128 + ko];
    fb[2] = *(const bf16x8*)&WabT[(128 + colw + l15) * 128 + ko];
    fb[3] = *(const bf16x8*)&WabT[(128 + colw + 16 + l15) * 128 + ko];
    #pragma unroll
    for (int mt = 0; mt < 4; ++mt)
      #pragma unroll
      for (int nt = 0; nt < 4; ++nt)
        acc1[mt][nt] = MFMA16(fa[mt], fb[nt], acc1[mt][nt]);
  }
  // write back A now (R0 is dead since the phase-1 barrier)
  #pragma unroll
  for (int mt = 0; mt < 4; ++mt)
    #pragma unroll
    for (int nt = 0; nt < 2; ++nt) {
      int col = colw + nt * 16 + l15;
      #pragma unroll
      for (int r = 0; r < 4; ++r)
        Ab[(mt * 16 + quad * 4 + r) * LROW + col] = (__bf16)acc1[mt][nt][r];
    }

  // ---- phase 2 pass 2: D cols colw..colw+31 = h1 @ WdT (8 accs, live to phase 5)
  f32x4 accD[4][2];
  {
    f32x4 zero = {0.f, 0.f, 0.f, 0.f};
    #pragma unroll
    for (int mt = 0; mt < 4; ++mt) { accD[mt][0] = zero; accD[mt][1] = zero; }
  }
  #pragma unroll
  for (int kb = 0; kb < 128; kb += 32) {
    const int ko = kb + quad * 8;
    bf16x8 fa[4], fd[2];
    #pragma unroll
    for (int mt = 0; mt < 4; ++mt)
      fa[mt] = *(const bf16x8*)&h1[(mt * 16 + l15) * LROW + ko];
    fd[0] = *(const bf16x8*)&WdT[(colw + l15) * 128 + ko];
    fd[1] = *(const bf16x8*)&WdT[(colw + 16 + l15) * 128 + ko];
    #pragma unroll
    for (int mt = 0; mt < 4; ++mt) {
      accD[mt][0] = MFMA16(fa[mt], fd[0], accD[mt][0]);
      accD[mt][1] = MFMA16(fa[mt], fd[1], accD[mt][1]);
    }
  }
  __syncthreads();   // all waves done reading h1
  // write back B over the dead h1 region
  #pragma unroll
  for (int mt = 0; mt < 4; ++mt)
    #pragma unroll
    for (int nt = 2; nt < 4; ++nt) {
      int col = colw + (nt - 2) * 16 + l15;
      #pragma unroll
      for (int r = 0; r < 4; ++r)
        Bb[(mt * 16 + quad * 4 + r) * LROW + col] = (__bf16)acc1[mt][nt][r];
    }
  __syncthreads();

  // ---- phase 4: edges, packed f32x2. S[i] = sum_{j!=i} relu(A[i]+B[j]+d_ij*w1d+cAB).
  //      S overwrites A in-place (each thread owns its (row, 4-col) slice).
  {
    const int g   = tid >> 5;          // graph 0..7
    const int nb4 = (tid & 31) * 4;    // 4 hidden dims per thread (2 f32x2 pairs)
    const f32x2 w0 = *(const f32x2*)&vec[nb4];
    const f32x2 w1 = *(const f32x2*)&vec[nb4 + 2];
    const f32x2 c0 = *(const f32x2*)&vec[128 + nb4];
    const f32x2 c1 = *(const f32x2*)&vec[128 + nb4 + 2];
    const f32x2 z2 = {0.f, 0.f};
    f32x2 B0[8], B1[8];
    #pragma unroll
    for (int j = 0; j < 8; ++j) {
      uint2 vb = *(const uint2*)&Bb[(g * 8 + j) * LROW + nb4];
      B0[j].x = bflo(vb.x); B0[j].y = bfhi(vb.x);
      B1[j].x = bflo(vb.y); B1[j].y = bfhi(vb.y);
    }
    #pragma unroll
    for (int i = 0; i < 8; ++i) {
      uint2 va = *(const uint2*)&Ab[(g * 8 + i) * LROW + nb4];
      f32x2 a0; a0.x = bflo(va.x); a0.y = bfhi(va.x); a0 += c0;
      f32x2 a1; a1.x = bflo(va.y); a1.y = bfhi(va.y); a1 += c1;
      f32x2 s0 = z2, s1 = z2;
      #pragma unroll
      for (int j = 0; j < 8; ++j) {
        if (j == i) continue;
        float d = dist[g * 64 + i * 8 + j];
        f32x2 d2 = {d, d};
        f32x2 t0 = __builtin_elementwise_fma(d2, w0, B0[j]) + a0;
        f32x2 t1 = __builtin_elementwise_fma(d2, w1, B1[j]) + a1;
        t0 = __builtin_elementwise_max(t0, z2);
        t1 = __builtin_elementwise_max(t1, z2);
        s0 += t0; s1 += t1;
      }
      bf16x4v o = { (__bf16)s0.x, (__bf16)s0.y, (__bf16)s1.x, (__bf16)s1.y };
      *(bf16x4v*)&Ab[(g * 8 + i) * LROW + nb4] = o;   // in-place
    }
  }
  __syncthreads();

  // ---- phase 5: ph = relu(S@Wc + D + cP); per-graph sum -> Sph (pad rows zeroed)
  {
    const __bf16* Sb = Ab;
    #pragma unroll
    for (int kb = 0; kb < 128; kb += 32) {
      const int ko = kb + quad * 8;
      bf16x8 fa[4], fc[2];
      #pragma unroll
      for (int mt = 0; mt < 4; ++mt)
        fa[mt] = *(const bf16x8*)&Sb[(mt * 16 + l15) * LROW + ko];
      fc[0] = *(const bf16x8*)&WcT[(colw + l15) * 128 + ko];
      fc[1] = *(const bf16x8*)&WcT[(colw + 16 + l15) * 128 + ko];
      #pragma unroll
      for (int mt = 0; mt < 4; ++mt) {
        accD[mt][0] = MFMA16(fa[mt], fc[0], accD[mt][0]);
        accD[mt][1] = MFMA16(fa[mt], fc[1], accD[mt][1]);
      }
    }
    #pragma unroll
    for (int mt = 0; mt < 4; ++mt)
      #pragma unroll
      for (int dt = 0; dt < 2; ++dt) {
        int col = colw + dt * 16 + l15;
        float cp = vec[256 + col];
        f32x4 a = accD[mt][dt];
        float s = fmaxf(a[0] + cp, 0.f) + fmaxf(a[1] + cp, 0.f)
                + fmaxf(a[2] + cp, 0.f) + fmaxf(a[3] + cp, 0.f);
        s += __shfl_xor(s, 16);
        int grow = mt * 2 + (lane >= 32 ? 1 : 0);
        if ((lane & 31) < 16) Sph[grow * LROW + col] = (__bf16)s;
        else                  Sph[(8 + grow) * LROW + col] = (__bf16)0.f;
      }
  }
  __syncthreads();

  // ---- phase 6: ho = relu(Sph @ WO + cO)  (M=16 tile: 8 graphs + 8 zero rows)
  {
    f32x4 acco[2];
    f32x4 zero = {0.f, 0.f, 0.f, 0.f};
    acco[0] = zero; acco[1] = zero;
    #pragma unroll
    for (int kb = 0; kb < 128; kb += 32) {
      const int ko = kb + quad * 8;
      bf16x8 fa = *(const bf16x8*)&Sph[l15 * LROW + ko];
      bf16x8 fb0 = *(const bf16x8*)&WoT[(colw + l15) * 128 + ko];
      bf16x8 fb1 = *(const bf16x8*)&WoT[(colw + 16 + l15) * 128 + ko];
      acco[0] = MFMA16(fa, fb0, acco[0]);
      acco[1] = MFMA16(fa, fb1, acco[1]);
    }
    #pragma unroll
    for (int dt = 0; dt < 2; ++dt) {
      int col = colw + dt * 16 + l15;
      float co = vec[384 + col];
      #pragma unroll
      for (int r = 0; r < 4; ++r)
        hob[(quad * 4 + r) * LROW + col] = (__bf16)fmaxf(acco[dt][r] + co, 0.f);
    }
  }
  __syncthreads();

  // ---- phase 7: logits = ho @ out_W2 + out_b2  (wave 0 only)
  if (w == 0) {
    f32x4 accf = {0.f, 0.f, 0.f, 0.f};
    #pragma unroll
    for (int kb = 0; kb < 128; kb += 32) {
      const int ko = kb + quad * 8;
      bf16x8 fa  = *(const bf16x8*)&hob[l15 * LROW + ko];
      bf16x8 fbv = *(const bf16x8*)&Wo2T[l15 * 128 + ko];
      accf = MFMA16(fa, fbv, accf);
    }
    if (quad < 2) {
      float b2 = out_b2[l15];
      #pragma unroll
      for (int r = 0; r < 4; ++r) {
        int row = quad * 4 + r;
        out[(g0 + row) * 16 + l15] = accf[r] + b2;
      }
    }
  }
}

extern "C" void kernel_launch(void* const* d_in, const int* in_sizes, int n_in,
                              void* d_out, int out_size, void* d_ws, size_t ws_size,
                              hipStream_t stream) {
  const int*   anchors   = (const int*)d_in[0];
  const int*   n_jumps   = (const int*)d_in[1];
  const float* positions = (const float*)d_in[2];
  const int*   colors    = (const int*)d_in[3];
  const int*   markers   = (const int*)d_in[4];
  const float* pre_W1  = (const float*)d_in[5];
  const float* pre_b1  = (const float*)d_in[6];
  const float* pre_W2  = (const float*)d_in[7];
  const float* pre_b2  = (const float*)d_in[8];
  const float* msg_W1  = (const float*)d_in[9];
  const float* msg_b1  = (const float*)d_in[10];
  const float* msg_W2  = (const float*)d_in[11];
  const float* msg_b2  = (const float*)d_in[12];
  const float* post_W1 = (const float*)d_in[13];
  const float* post_b1 = (const float*)d_in[14];
  const float* post_W2 = (const float*)d_in[15];
  const float* post_b2 = (const float*)d_in[16];
  const float* out_W1  = (const float*)d_in[17];
  const float* out_b1  = (const float*)d_in[18];
  const float* out_W2  = (const float*)d_in[19];
  const float* out_b2  = (const float*)d_in[20];

  char* ws = (char*)d_ws;
  unsigned short* WabT = (unsigned short*)(ws);            // [256][128] bf16
  unsigned short* WdT  = (unsigned short*)(ws + 65536);    // [128][128]
  unsigned short* WcT  = (unsigned short*)(ws + 98304);    // [128][128]
  unsigned short* WoT  = (unsigned short*)(ws + 131072);   // [128][128]
  unsigned short* Wo2T = (unsigned short*)(ws + 163840);   // [16][128]
  float*          vecs = (float*)(ws + 167936);            // 512 f32

  const int BS = in_sizes[0];

  combine_weights<<<324, 256, 0, stream>>>(
      pre_W2, msg_W1, msg_W2, post_W1, post_W2, out_W1, out_W2,
      pre_b2, msg_b1, msg_b2, post_b1, post_b2, out_b1,
      WabT, WdT, WcT, WoT, Wo2T, vecs);

  rrn_main<<<BS / 8, 256, 0, stream>>>(
      anchors, n_jumps, positions, colors, markers, pre_W1, pre_b1,
      (const __bf16*)WabT, (const __bf16*)WdT, (const __bf16*)WcT,
      (const __bf16*)WoT, (const __bf16*)Wo2T, vecs, out_b2, (float*)d_out);
}